// Round 1
// baseline (10487.064 us; speedup 1.0000x reference)
//
#include <hip/hip_runtime.h>
#include <math.h>

#define IMG_H 1024
#define IMG_W 1024
#define NPIX (IMG_H * IMG_W)
#define TWO_PI_F 6.2831853071795864769f

__device__ __forceinline__ float gelu_exact(float x) {
    // 0.5 * x * (1 + erf(x / sqrt(2)))
    return 0.5f * x * (1.0f + erff(x * 0.70710678118654752440f));
}

__device__ __forceinline__ float sigmoid_f(float x) {
    return 1.0f / (1.0f + __expf(-x));
}

__global__ __launch_bounds__(256, 2) void vfx_decoder_kernel(
    const float* __restrict__ latent,   // [H*W, 4]
    const int*   __restrict__ raw_pos,  // [N, 2]
    const float* __restrict__ control,  // [N, 2]
    const float* __restrict__ W1, const float* __restrict__ b1,   // [108,64],[64]
    const float* __restrict__ W2, const float* __restrict__ b2,   // [64,128],[128]
    const float* __restrict__ W3, const float* __restrict__ b3,   // [128,64],[64]
    const float* __restrict__ W4, const float* __restrict__ b4,   // [64,4],[4]
    float* __restrict__ out)            // [N, 4]
{
    const int n = blockIdx.x * blockDim.x + threadIdx.x;
    if (n >= NPIX) return;

    const int px = raw_pos[2 * n + 0];
    const int py = raw_pos[2 * n + 1];
    const float c0 = control[2 * n + 0];
    const float c1 = control[2 * n + 1];

    // ---------------- Layer 1: stream 9 neighbors x 12 features ----------------
    float h1[64];
    #pragma unroll
    for (int j = 0; j < 64; ++j) h1[j] = b1[j];

    for (int kk = 0; kk < 9; ++kk) {
        const int dx = kk / 3 - 1;      // xo = offs[kk//3]
        const int dy = kk % 3 - 1;      // yo = offs[kk%3]
        const int ex = min(max(px + dx, 0), IMG_W - 1);
        const int ey = min(max(py + dy, 0), IMG_H - 1);
        const int lin = ey * IMG_W + ex;

        const float4 lat = *reinterpret_cast<const float4*>(latent + 4 * lin);
        const float xf = (float)ex * (1.0f / IMG_W);
        const float yf = (float)ey * (1.0f / IMG_H);

        float f[12];
        f[0] = lat.x; f[1] = lat.y; f[2] = lat.z; f[3] = lat.w;
        f[4] = xf;    f[5] = yf;
        f[6] = __sinf(TWO_PI_F * xf);
        f[7] = __sinf(TWO_PI_F * yf);
        f[8] = __sinf(2.0f * TWO_PI_F * xf);
        f[9] = __sinf(2.0f * TWO_PI_F * yf);
        f[10] = c0;   f[11] = c1;

        const float* __restrict__ w1blk = W1 + kk * 12 * 64;
        #pragma unroll
        for (int i = 0; i < 12; ++i) {
            const float fi = f[i];
            #pragma unroll
            for (int j = 0; j < 64; ++j)
                h1[j] = fmaf(fi, w1blk[i * 64 + j], h1[j]);
        }
    }
    #pragma unroll
    for (int j = 0; j < 64; ++j) h1[j] = gelu_exact(h1[j]);

    // ---------------- Layers 2+3: h2 (128) in two 64-halves folded into h3 -----
    float h3[64];
    #pragma unroll
    for (int j = 0; j < 64; ++j) h3[j] = b3[j];

    for (int half = 0; half < 2; ++half) {
        float h2[64];
        #pragma unroll
        for (int j = 0; j < 64; ++j) h2[j] = b2[half * 64 + j];

        #pragma unroll
        for (int i = 0; i < 64; ++i) {
            const float hi = h1[i];
            #pragma unroll
            for (int j = 0; j < 64; ++j)
                h2[j] = fmaf(hi, W2[i * 128 + half * 64 + j], h2[j]);
        }
        #pragma unroll
        for (int j = 0; j < 64; ++j) h2[j] = gelu_exact(h2[j]);

        #pragma unroll
        for (int i = 0; i < 64; ++i) {
            const float hi = h2[i];
            #pragma unroll
            for (int j = 0; j < 64; ++j)
                h3[j] = fmaf(hi, W3[(half * 64 + i) * 64 + j], h3[j]);
        }
    }
    #pragma unroll
    for (int j = 0; j < 64; ++j) h3[j] = gelu_exact(h3[j]);

    // ---------------- Layer 4: 64 -> 4, sigmoid ----------------
    float o0 = b4[0], o1 = b4[1], o2 = b4[2], o3 = b4[3];
    #pragma unroll
    for (int i = 0; i < 64; ++i) {
        const float hi = h3[i];
        o0 = fmaf(hi, W4[i * 4 + 0], o0);
        o1 = fmaf(hi, W4[i * 4 + 1], o1);
        o2 = fmaf(hi, W4[i * 4 + 2], o2);
        o3 = fmaf(hi, W4[i * 4 + 3], o3);
    }

    float4 res;
    res.x = sigmoid_f(o0);
    res.y = sigmoid_f(o1);
    res.z = sigmoid_f(o2);
    res.w = sigmoid_f(o3);
    *reinterpret_cast<float4*>(out + 4 * n) = res;
}

extern "C" void kernel_launch(void* const* d_in, const int* in_sizes, int n_in,
                              void* d_out, int out_size, void* d_ws, size_t ws_size,
                              hipStream_t stream) {
    const float* latent  = (const float*)d_in[0];
    const int*   raw_pos = (const int*)  d_in[1];
    const float* control = (const float*)d_in[2];
    const float* W1 = (const float*)d_in[3];
    const float* b1 = (const float*)d_in[4];
    const float* W2 = (const float*)d_in[5];
    const float* b2 = (const float*)d_in[6];
    const float* W3 = (const float*)d_in[7];
    const float* b3 = (const float*)d_in[8];
    const float* W4 = (const float*)d_in[9];
    const float* b4 = (const float*)d_in[10];
    float* out = (float*)d_out;

    dim3 grid((NPIX + 255) / 256);
    dim3 block(256);
    vfx_decoder_kernel<<<grid, block, 0, stream>>>(
        latent, raw_pos, control, W1, b1, W2, b2, W3, b3, W4, b4, out);
}

// Round 2
// 311.184 us; speedup vs baseline: 33.7005x; 33.7005x over previous
//
#include <hip/hip_runtime.h>
#include <math.h>

#define IMG 1024
#define NPIXTOT (IMG * IMG)

typedef __attribute__((ext_vector_type(8))) short short8;
typedef __attribute__((ext_vector_type(4))) float f32x4;
typedef unsigned int uint;
typedef unsigned short ushort;

// bf16 weight image in d_ws (elements). Layout per layer: [K/8][N][8] k-blocked,
// so a B-fragment (col=lane&15, k=8*hi+i) is one ds_read_b128.
#define W1_OFF 0        // [16][64][8]  K=128 (pad from 108 with zeros)
#define W2_OFF 8192     // [8][128][8]  K=64
#define W3_OFF 16384    // [16][64][8]  K=128
#define W4_OFF 24576    // [8][16][8]   K=64, N padded 4->16 with zeros
#define WTOT   25600    // elements (51200 bytes)

#define XSTR   (16 * 32 * 8)           // per-wave X buffer: 16 kb x 32 pix x 8 = 4096 els
#define LDS_BYTES ((WTOT + 8 * XSTR) * 2)   // 25600 + 32768 els = 116736 B

__device__ __forceinline__ ushort f2bf(float f) {        // RTN f32->bf16
    uint u = __float_as_uint(f);
    u += 0x7fffu + ((u >> 16) & 1u);
    return (ushort)(u >> 16);
}
__device__ __forceinline__ float gelu_exact(float v) {
    return 0.5f * v * (1.0f + erff(v * 0.70710678118654752440f));
}

__global__ void prep_weights(const float* __restrict__ W1, const float* __restrict__ W2,
                             const float* __restrict__ W3, const float* __restrict__ W4,
                             ushort* __restrict__ ws) {
    int e = blockIdx.x * 256 + threadIdx.x;
    if (e >= WTOT) return;
    float v;
    if (e < W2_OFF) {                       // W1: [16][64][8], k = kb*8+i, zero for k>=108
        int kb = e >> 9, n = (e >> 3) & 63, i = e & 7, k = kb * 8 + i;
        v = (k < 108) ? W1[k * 64 + n] : 0.0f;
    } else if (e < W3_OFF) {                // W2: [8][128][8]
        int r = e - W2_OFF;
        int kb = r >> 10, n = (r >> 3) & 127, i = r & 7, k = kb * 8 + i;
        v = W2[k * 128 + n];
    } else if (e < W4_OFF) {                // W3: [16][64][8]
        int r = e - W3_OFF;
        int kb = r >> 9, n = (r >> 3) & 63, i = r & 7, k = kb * 8 + i;
        v = W3[k * 64 + n];
    } else {                                // W4: [8][16][8], zero for n>=4
        int r = e - W4_OFF;
        int kb = r >> 7, n = (r >> 3) & 15, i = r & 7, k = kb * 8 + i;
        v = (n < 4) ? W4[k * 4 + n] : 0.0f;
    }
    ws[e] = f2bf(v);
}

// One MLP layer for one wave: X (LDS, k-blocked [16][32][8]) @ W (LDS) -> X in place.
// KS = K/32 k-steps, NT = Nout/16 n-tiles, NW = weight image row count.
// All A-fragments preloaded to registers => in-place writeback is race-free by dataflow.
template<int KS, int NT, int NW>
__device__ __forceinline__ void mlayer(ushort* __restrict__ xw, const ushort* __restrict__ wblk,
                                       const float* __restrict__ bias, int lane) {
    const int lo = lane & 15, hi = lane >> 4;
    short8 a[2][KS];
    #pragma unroll
    for (int m = 0; m < 2; ++m)
        #pragma unroll
        for (int ks = 0; ks < KS; ++ks)
            a[m][ks] = *(const short8*)&xw[(((ks * 4 + hi) * 32) + m * 16 + lo) * 8];

    #pragma unroll
    for (int nt = 0; nt < NT; ++nt) {
        const float bv = bias[nt * 16 + lo];
        f32x4 acc0 = {bv, bv, bv, bv};
        f32x4 acc1 = acc0;
        #pragma unroll
        for (int ks = 0; ks < KS; ++ks) {
            short8 b = *(const short8*)&wblk[(((ks * 4 + hi) * NW) + nt * 16 + lo) * 8];
            acc0 = __builtin_amdgcn_mfma_f32_16x16x32_bf16(a[0][ks], b, acc0, 0, 0, 0);
            acc1 = __builtin_amdgcn_mfma_f32_16x16x32_bf16(a[1][ks], b, acc1, 0, 0, 0);
        }
        // D layout: col = lo (neuron within tile), rows = pixel 4*hi + r
        const int e = nt * 16 + lo, kb = e >> 3, off = e & 7;
        #pragma unroll
        for (int r = 0; r < 4; ++r) {
            xw[((kb * 32) + 0 * 16 + hi * 4 + r) * 8 + off] = f2bf(gelu_exact(acc0[r]));
            xw[((kb * 32) + 1 * 16 + hi * 4 + r) * 8 + off] = f2bf(gelu_exact(acc1[r]));
        }
    }
}

__global__ __launch_bounds__(512, 2) void vfx_mfma(
    const float* __restrict__ latent, const int* __restrict__ raw_pos,
    const float* __restrict__ control, const ushort* __restrict__ wsw,
    const float* __restrict__ b1, const float* __restrict__ b2,
    const float* __restrict__ b3, const float* __restrict__ b4,
    float* __restrict__ out)
{
    extern __shared__ ushort lds[];
    const int tid = threadIdx.x;
    const int wave = tid >> 6, lane = tid & 63;
    const int lo = lane & 15, hi = lane >> 4;

    // ---- stage bf16 weight image (51200 B) into LDS ----
    {
        const uint4* src = (const uint4*)wsw;
        uint4* dst = (uint4*)lds;
        for (int i = tid; i < 3200; i += 512) dst[i] = src[i];
    }

    ushort* xw = lds + WTOT + wave * XSTR;
    const int pixbase = blockIdx.x * 256 + wave * 32;

    // ---- build 108 input features for this wave's 32 pixels ----
    {
        const int p = lane & 31;
        const int g = pixbase + p;
        const int px = raw_pos[2 * g], py = raw_pos[2 * g + 1];
        const float c0 = control[2 * g], c1 = control[2 * g + 1];
        const int nb0 = (lane < 32) ? 0 : 5;
        const int nbn = (lane < 32) ? 5 : 4;
        for (int t = 0; t < nbn; ++t) {
            const int nb = nb0 + t;
            const int ex = min(max(px + nb / 3 - 1, 0), IMG - 1);
            const int ey = min(max(py + (nb % 3) - 1, 0), IMG - 1);
            const float4 lat = ((const float4*)latent)[ey * IMG + ex];
            const float xf = ex * (1.0f / IMG), yf = ey * (1.0f / IMG);
            float f[12] = {lat.x, lat.y, lat.z, lat.w, xf, yf,
                           __sinf(6.28318530718f * xf), __sinf(6.28318530718f * yf),
                           __sinf(12.5663706144f * xf), __sinf(12.5663706144f * yf),
                           c0, c1};
            #pragma unroll
            for (int j = 0; j < 6; ++j) {
                const int e = nb * 12 + 2 * j;   // even => aligned uint
                const uint u = (uint)f2bf(f[2 * j]) | ((uint)f2bf(f[2 * j + 1]) << 16);
                *(uint*)&xw[((e >> 3) * 32 + p) * 8 + (e & 7)] = u;
            }
        }
        if (lane < 32) {   // zero-pad k = 108..127
            #pragma unroll
            for (int e = 108; e < 128; e += 2)
                *(uint*)&xw[((e >> 3) * 32 + p) * 8 + (e & 7)] = 0u;
        }
    }
    __syncthreads();   // covers weight staging + X build

    mlayer<4, 4, 64>(xw, lds + W1_OFF, b1, lane);    // 108(128) -> 64
    __syncthreads();
    mlayer<2, 8, 128>(xw, lds + W2_OFF, b2, lane);   // 64 -> 128
    __syncthreads();
    mlayer<4, 4, 64>(xw, lds + W3_OFF, b3, lane);    // 128 -> 64
    __syncthreads();

    // ---- layer 4: 64 -> 4 (padded 16), sigmoid, store ----
    {
        const float bv = (lo < 4) ? b4[lo] : 0.0f;
        f32x4 acc0 = {bv, bv, bv, bv};
        f32x4 acc1 = acc0;
        #pragma unroll
        for (int ks = 0; ks < 2; ++ks) {
            short8 am0 = *(const short8*)&xw[(((ks * 4 + hi) * 32) + lo) * 8];
            short8 am1 = *(const short8*)&xw[(((ks * 4 + hi) * 32) + 16 + lo) * 8];
            short8 b   = *(const short8*)&lds[W4_OFF + (((ks * 4 + hi) * 16) + lo) * 8];
            acc0 = __builtin_amdgcn_mfma_f32_16x16x32_bf16(am0, b, acc0, 0, 0, 0);
            acc1 = __builtin_amdgcn_mfma_f32_16x16x32_bf16(am1, b, acc1, 0, 0, 0);
        }
        if (lo < 4) {
            #pragma unroll
            for (int r = 0; r < 4; ++r) {
                const int p0 = pixbase + hi * 4 + r;
                const int p1 = pixbase + 16 + hi * 4 + r;
                out[p0 * 4 + lo] = 1.0f / (1.0f + __expf(-acc0[r]));
                out[p1 * 4 + lo] = 1.0f / (1.0f + __expf(-acc1[r]));
            }
        }
    }
}

extern "C" void kernel_launch(void* const* d_in, const int* in_sizes, int n_in,
                              void* d_out, int out_size, void* d_ws, size_t ws_size,
                              hipStream_t stream) {
    const float* latent  = (const float*)d_in[0];
    const int*   raw_pos = (const int*)  d_in[1];
    const float* control = (const float*)d_in[2];
    const float* W1 = (const float*)d_in[3];
    const float* b1 = (const float*)d_in[4];
    const float* W2 = (const float*)d_in[5];
    const float* b2 = (const float*)d_in[6];
    const float* W3 = (const float*)d_in[7];
    const float* b3 = (const float*)d_in[8];
    const float* W4 = (const float*)d_in[9];
    const float* b4 = (const float*)d_in[10];
    float* out = (float*)d_out;
    ushort* ws = (ushort*)d_ws;

    static bool attr_set = false;   // idempotent attribute set (not a stream op)
    hipFuncSetAttribute((const void*)vfx_mfma,
                        hipFuncAttributeMaxDynamicSharedMemorySize, LDS_BYTES);

    prep_weights<<<dim3((WTOT + 255) / 256), dim3(256), 0, stream>>>(W1, W2, W3, W4, ws);

    dim3 grid(NPIXTOT / 256);   // 4096 blocks x 512 threads, 256 pixels/block
    vfx_mfma<<<grid, dim3(512), LDS_BYTES, stream>>>(
        latent, raw_pos, control, ws, b1, b2, b3, b4, out);
}

// Round 3
// 149.545 us; speedup vs baseline: 70.1264x; 2.0809x over previous
//
#include <hip/hip_runtime.h>
#include <hip/hip_bf16.h>
#include <math.h>

#define IMG 1024
#define NPIXTOT (IMG * IMG)
#define TWO_PI_F 6.28318530717958647692f

typedef __attribute__((ext_vector_type(8))) short short8;
typedef __attribute__((ext_vector_type(4))) float f32x4;
typedef unsigned int uint;
typedef unsigned short ushort;

// A-fragment weight image (W^T) in d_ws, bf16. Per layer: [nt*KS+ks][hi(4)][lo(16)][i(8)]
// so lane (lo,hi)'s A-frag (row m=16nt+lo, k=32ks+8hi+i) is one 16B load.
#define A1_OFF 0        // W1^T: KS=4, NT=4  (K 108->128 zero-pad)   8192 els
#define A2_OFF 8192     // W2^T: KS=2, NT=8                          8192 els
#define A3_OFF 16384    // W3^T: KS=4, NT=4                          8192 els
#define A4_OFF 24576    // W4^T: KS=2, NT=1  (m 4->16 zero-pad)      1024 els
#define WTOT   25600

#define XROW 136        // padded K stride in elements (272 B = 17*16 -> bank-friendly)

__device__ __forceinline__ ushort f2bf(float f) {   // RNE f32->bf16
    uint u = __float_as_uint(f);
    u += 0x7fffu + ((u >> 16) & 1u);
    return (ushort)(u >> 16);
}

__device__ __forceinline__ uint pack2(float a, float b) {  // 2xf32 -> packed bf16x2
    float2 t; t.x = a; t.y = b;
    __hip_bfloat162 h = __float22bfloat162_rn(t);
    union { __hip_bfloat162 h; uint u; } cv; cv.h = h;
    return cv.u;
}

// gelu(x) ~= x * sigmoid(1.5957691x + 0.0713548x^3); branchless, ~7 VALU instr
__device__ __forceinline__ float gelu_fast(float x) {
    float u = x * x;
    float p = fmaf(u, -0.0713548162f, -1.5957691216f);
    float e = __expf(x * p);
    return x * __builtin_amdgcn_rcpf(1.0f + e);
}
__device__ __forceinline__ float sig_fast(float x) {
    return __builtin_amdgcn_rcpf(1.0f + __expf(-x));
}

__global__ void prep_weights(const float* __restrict__ W1, const float* __restrict__ W2,
                             const float* __restrict__ W3, const float* __restrict__ W4,
                             ushort* __restrict__ ws) {
    int e = blockIdx.x * 256 + threadIdx.x;
    if (e >= WTOT) return;
    float v;
    if (e < A2_OFF) {                       // W1 [108][64], K padded to 128
        int r = e, i = r & 7, lo = (r >> 3) & 15, hi = (r >> 7) & 3, kst = r >> 9;
        int nt = kst >> 2, ks = kst & 3;
        int m = nt * 16 + lo, k = ks * 32 + hi * 8 + i;
        v = (k < 108) ? W1[k * 64 + m] : 0.0f;
    } else if (e < A3_OFF) {                // W2 [64][128]
        int r = e - A2_OFF, i = r & 7, lo = (r >> 3) & 15, hi = (r >> 7) & 3, kst = r >> 9;
        int nt = kst >> 1, ks = kst & 1;
        int m = nt * 16 + lo, k = ks * 32 + hi * 8 + i;
        v = W2[k * 128 + m];
    } else if (e < A4_OFF) {                // W3 [128][64]
        int r = e - A3_OFF, i = r & 7, lo = (r >> 3) & 15, hi = (r >> 7) & 3, kst = r >> 9;
        int nt = kst >> 2, ks = kst & 3;
        int m = nt * 16 + lo, k = ks * 32 + hi * 8 + i;
        v = W3[k * 64 + m];
    } else {                                // W4 [64][4], m padded to 16
        int r = e - A4_OFF, i = r & 7, lo = (r >> 3) & 15, hi = (r >> 7) & 3, ks = (r >> 9) & 1;
        int m = lo, k = ks * 32 + hi * 8 + i;
        v = (m < 4) ? W4[k * 4 + m] : 0.0f;
    }
    ws[e] = f2bf(v);
}

// One layer: D = W^T (A, from global) x X^T (B, from wave-private LDS), in-place.
// All B-frags preloaded to regs => in-place writeback race-free by dataflow.
template<int KS, int NT>
__device__ __forceinline__ void mlayer(ushort* xw, const ushort* __restrict__ wA,
                                       const float* __restrict__ bias, int lo, int hi) {
    short8 b[2][KS];
    #pragma unroll
    for (int pt = 0; pt < 2; ++pt)
        #pragma unroll
        for (int ks = 0; ks < KS; ++ks)
            b[pt][ks] = *(const short8*)&xw[(pt * 16 + lo) * XROW + ks * 32 + hi * 8];

    #pragma unroll
    for (int nt = 0; nt < NT; ++nt) {
        const float4 bv = *(const float4*)&bias[nt * 16 + hi * 4];
        f32x4 acc0 = {bv.x, bv.y, bv.z, bv.w};
        f32x4 acc1 = acc0;
        #pragma unroll
        for (int ks = 0; ks < KS; ++ks) {
            const short8 a = *(const short8*)&wA[(nt * KS + ks) * 512 + (hi * 16 + lo) * 8];
            acc0 = __builtin_amdgcn_mfma_f32_16x16x32_bf16(a, b[0][ks], acc0, 0, 0, 0);
            acc1 = __builtin_amdgcn_mfma_f32_16x16x32_bf16(a, b[1][ks], acc1, 0, 0, 0);
        }
        // lane holds rows m = nt*16 + 4*hi + r (4 consecutive k of next layer), col = pixel
        uint2 w;
        w.x = pack2(gelu_fast(acc0[0]), gelu_fast(acc0[1]));
        w.y = pack2(gelu_fast(acc0[2]), gelu_fast(acc0[3]));
        *(uint2*)&xw[lo * XROW + nt * 16 + hi * 4] = w;
        w.x = pack2(gelu_fast(acc1[0]), gelu_fast(acc1[1]));
        w.y = pack2(gelu_fast(acc1[2]), gelu_fast(acc1[3]));
        *(uint2*)&xw[(16 + lo) * XROW + nt * 16 + hi * 4] = w;
    }
}

__global__ __launch_bounds__(256, 4) void vfx_mfma(
    const float* __restrict__ latent, const int* __restrict__ raw_pos,
    const float* __restrict__ control, const ushort* __restrict__ wA,
    const float* __restrict__ b1, const float* __restrict__ b2,
    const float* __restrict__ b3, const float* __restrict__ b4,
    float* __restrict__ out)
{
    __shared__ ushort lds[4 * 32 * XROW];   // 34,816 B -> 4 blocks/CU
    const int tid = threadIdx.x;
    const int wave = tid >> 6, lane = tid & 63;
    const int lo = lane & 15, hi = lane >> 4;
    ushort* xw = lds + wave * 32 * XROW;
    const int pixbase = blockIdx.x * 128 + wave * 32;

    // ---- build X^T: row = pixel (32), k = 0..107 features, 108..127 zero ----
    {
        const int p = lane & 31;
        const int g = pixbase + p;
        const int px = raw_pos[2 * g], py = raw_pos[2 * g + 1];
        const float c0 = control[2 * g], c1 = control[2 * g + 1];
        ushort* xrow = xw + p * XROW;
        const int nb0 = (lane < 32) ? 0 : 5;
        const int nbn = (lane < 32) ? 5 : 4;
        for (int t = 0; t < nbn; ++t) {
            const int nb = nb0 + t;
            const int ex = min(max(px + nb / 3 - 1, 0), IMG - 1);
            const int ey = min(max(py + (nb % 3) - 1, 0), IMG - 1);
            const float4 lat = ((const float4*)latent)[ey * IMG + ex];
            const float xf = ex * (1.0f / IMG), yf = ey * (1.0f / IMG);
            const int e = nb * 12;
            *(uint*)&xrow[e + 0]  = pack2(lat.x, lat.y);
            *(uint*)&xrow[e + 2]  = pack2(lat.z, lat.w);
            *(uint*)&xrow[e + 4]  = pack2(xf, yf);
            *(uint*)&xrow[e + 6]  = pack2(__sinf(TWO_PI_F * xf), __sinf(TWO_PI_F * yf));
            *(uint*)&xrow[e + 8]  = pack2(__sinf(2.0f * TWO_PI_F * xf), __sinf(2.0f * TWO_PI_F * yf));
            *(uint*)&xrow[e + 10] = pack2(c0, c1);
        }
        if (lane >= 32) {
            #pragma unroll
            for (int e = 108; e < 128; e += 2) *(uint*)&xrow[e] = 0u;
        }
    }
    // waves are private to their X buffer: no barriers anywhere

    mlayer<4, 4>(xw, wA + A1_OFF, b1, lo, hi);   // 128 -> 64
    mlayer<2, 8>(xw, wA + A2_OFF, b2, lo, hi);   // 64  -> 128
    mlayer<4, 4>(xw, wA + A3_OFF, b3, lo, hi);   // 128 -> 64

    // ---- layer 4: 64 -> 4 (m-padded 16), sigmoid, float4 store ----
    {
        float4 bv = {0.f, 0.f, 0.f, 0.f};
        if (hi == 0) bv = *(const float4*)b4;
        f32x4 acc0 = {bv.x, bv.y, bv.z, bv.w};
        f32x4 acc1 = acc0;
        #pragma unroll
        for (int ks = 0; ks < 2; ++ks) {
            const short8 a  = *(const short8*)&wA[A4_OFF + (ks * 64 + hi * 16 + lo) * 8];
            const short8 x0 = *(const short8*)&xw[lo * XROW + ks * 32 + hi * 8];
            const short8 x1 = *(const short8*)&xw[(16 + lo) * XROW + ks * 32 + hi * 8];
            acc0 = __builtin_amdgcn_mfma_f32_16x16x32_bf16(a, x0, acc0, 0, 0, 0);
            acc1 = __builtin_amdgcn_mfma_f32_16x16x32_bf16(a, x1, acc1, 0, 0, 0);
        }
        if (hi == 0) {   // rows 0..3 = the 4 real outputs, col = pixel lo
            float4 o;
            o.x = sig_fast(acc0[0]); o.y = sig_fast(acc0[1]);
            o.z = sig_fast(acc0[2]); o.w = sig_fast(acc0[3]);
            *(float4*)&out[(pixbase + lo) * 4] = o;
            o.x = sig_fast(acc1[0]); o.y = sig_fast(acc1[1]);
            o.z = sig_fast(acc1[2]); o.w = sig_fast(acc1[3]);
            *(float4*)&out[(pixbase + 16 + lo) * 4] = o;
        }
    }
}

extern "C" void kernel_launch(void* const* d_in, const int* in_sizes, int n_in,
                              void* d_out, int out_size, void* d_ws, size_t ws_size,
                              hipStream_t stream) {
    const float* latent  = (const float*)d_in[0];
    const int*   raw_pos = (const int*)  d_in[1];
    const float* control = (const float*)d_in[2];
    const float* W1 = (const float*)d_in[3];
    const float* b1 = (const float*)d_in[4];
    const float* W2 = (const float*)d_in[5];
    const float* b2 = (const float*)d_in[6];
    const float* W3 = (const float*)d_in[7];
    const float* b3 = (const float*)d_in[8];
    const float* W4 = (const float*)d_in[9];
    const float* b4 = (const float*)d_in[10];
    float* out = (float*)d_out;
    ushort* ws = (ushort*)d_ws;

    prep_weights<<<dim3((WTOT + 255) / 256), dim3(256), 0, stream>>>(W1, W2, W3, W4, ws);

    dim3 grid(NPIXTOT / 128);   // 8192 blocks x 256 threads, 128 pixels/block
    vfx_mfma<<<grid, dim3(256), 0, stream>>>(
        latent, raw_pos, control, ws, b1, b2, b3, b4, out);
}